// Round 2
// baseline (620.328 us; speedup 1.0000x reference)
//
#include <hip/hip_runtime.h>

typedef float f32x4 __attribute__((ext_vector_type(4)));
typedef float f32x16 __attribute__((ext_vector_type(16)));
typedef __bf16 bf16x8 __attribute__((ext_vector_type(8)));
typedef unsigned u32x4 __attribute__((ext_vector_type(4)));

__device__ __forceinline__ unsigned f2mono(float f) {
  unsigned u = __float_as_uint(f);
  return (u & 0x80000000u) ? ~u : (u | 0x80000000u);
}
__device__ __forceinline__ float mono2f(unsigned u) {
  return (u & 0x80000000u) ? __uint_as_float(u & 0x7fffffffu) : __uint_as_float(~u);
}
__device__ __forceinline__ float lrelu(float x) { return fmaxf(x, 0.2f * x); }
__device__ __forceinline__ unsigned pkhh(unsigned a, unsigned b) {
  return (a >> 16) | (b & 0xffff0000u);
}
__device__ __forceinline__ bf16x8 asbf8(u32x4 u) { return __builtin_bit_cast(bf16x8, u); }
__device__ __forceinline__ float truncbf(float x, unsigned& hbits) {
  hbits = __float_as_uint(x) & 0xffff0000u;
  return __uint_as_float(hbits);
}

// ---------------- init: global_feats = mono(-1e9) ----------------
__global__ void sc_init(unsigned* __restrict__ gf, int total4) {
  int i = blockIdx.x * blockDim.x + threadIdx.x;
  if (i < total4) {
    unsigned m = f2mono(-1.0e9f);
    ((uint4*)gf)[i] = make_uint4(m, m, m, m);
  }
}

// ---------------- fused: gather + L1(MFMA, bias folded) + L2(split-bf16 MFMA) + seg-amax ----
// Each wave independently owns 32-point tiles. No barriers in the main loop.
__global__ __launch_bounds__(256, 3) void sc_main(
    const float* __restrict__ muons, const int* __restrict__ bidx,
    const float* __restrict__ cond, const float* __restrict__ W1,
    const float* __restrict__ b1, const float* __restrict__ W2,
    const float* __restrict__ b2, unsigned* __restrict__ gf, int N) {
  __shared__ __align__(16) __bf16 w2h[8192];  // [kc=8][j=128][e=8] blocked, linear reads
  __shared__ __align__(16) __bf16 w2l[8192];
  __shared__ __align__(16) __bf16 w1e[2048];  // [kc=4][j=64][e=8] extended W1 (hi|hi|lo|bias)

  const int t = threadIdx.x;
  const int w = t >> 6;
  const int lane = t & 63;
  const int col = lane & 31;
  const int kh2 = lane >> 5;

  // ---- one-time weight staging ----
  {
    const int j = t & 127, kh = t >> 7;
    for (int kk = 0; kk < 32; ++kk) {
      const int k = kh * 32 + kk;
      const float v = W2[k * 128 + j];
      const __bf16 hb = (__bf16)v;
      const __bf16 lb = (__bf16)(v - (float)hb);
      const int idx = ((k >> 3) * 128 + j) * 8 + (k & 7);
      w2h[idx] = hb;
      w2l[idx] = lb;
    }
  }
  {
    // extended A1[j][k']: k'=0..6 W1h, 7..13 W1h, 14..20 W1l, 21 b1h, 22 b1l, else 0
    const int j = t & 63, kc = t >> 6;
    for (int e = 0; e < 8; ++e) {
      const int kp = kc * 8 + e;
      float val = 0.0f;
      unsigned hb;
      if (kp < 7)        { val = truncbf(W1[kp * 64 + j], hb); }
      else if (kp < 14)  { val = truncbf(W1[(kp - 7) * 64 + j], hb); }
      else if (kp < 21)  { float x = W1[(kp - 14) * 64 + j]; val = x - truncbf(x, hb); }
      else if (kp == 21) { val = truncbf(b1[j], hb); }
      else if (kp == 22) { float x = b1[j]; val = x - truncbf(x, hb); }
      w1e[(kc * 64 + j) * 8 + e] = (__bf16)val;
    }
  }
  __syncthreads();

  // hoist static per-lane data
  bf16x8 w1f[2][2];
  #pragma unroll
  for (int jt = 0; jt < 2; ++jt)
    #pragma unroll
    for (int mf = 0; mf < 2; ++mf)
      w1f[jt][mf] = *(const bf16x8*)&w1e[(((mf * 2 + kh2) * 64) + jt * 32 + col) * 8];
  float b2v[4];
  #pragma unroll
  for (int jt = 0; jt < 4; ++jt) b2v[jt] = b2[jt * 32 + col];

  const int ntiles = (N + 31) >> 5;
  const int gw = blockIdx.x * 4 + w;
  const int nw = gridDim.x * 4;
  for (int tile = gw; tile < ntiles; tile += nw) {
    const int pbase = tile << 5;
    const int p = pbase + col;
    const int pc = min(p, N - 1);
    const int bi = bidx[pc];

    // ---- load + decompose point inputs ----
    float in[7];
    in[0] = muons[pc * 3 + 0];
    in[1] = muons[pc * 3 + 1];
    in[2] = muons[pc * 3 + 2];
    const f32x4 c4 = *(const f32x4*)&cond[bi * 4];
    in[3] = c4.x; in[4] = c4.y; in[5] = c4.z; in[6] = c4.w;
    unsigned hu[7], lu[7];
    #pragma unroll
    for (int f = 0; f < 7; ++f) {
      const float hf = truncbf(in[f], hu[f]);
      lu[f] = __float_as_uint(in[f] - hf);
    }
    // B1 fragments (col = point): K' = [inh(7) | inl(7) | inh(7) | b-slots | 0]
    u32x4 f0a = { pkhh(hu[0], hu[1]), pkhh(hu[2], hu[3]), pkhh(hu[4], hu[5]), pkhh(hu[6], lu[0]) };
    u32x4 f0b = { pkhh(lu[1], lu[2]), pkhh(lu[3], lu[4]), pkhh(lu[5], lu[6]), f0a.x };
    u32x4 f1a = { f0a.y, f0a.z, (hu[6] >> 16) | 0x3F800000u, 0x00003F80u };
    u32x4 bf0u, bf1u;
    #pragma unroll
    for (int e2 = 0; e2 < 4; ++e2) {
      bf0u[e2] = kh2 ? f0b[e2] : f0a[e2];
      bf1u[e2] = kh2 ? 0u : f1a[e2];
    }
    const bf16x8 bfr0 = asbf8(bf0u), bfr1 = asbf8(bf1u);

    // ---- layer1: D1[j][p], bias folded ----
    f32x16 acc0, acc1;
    #pragma unroll
    for (int e = 0; e < 16; ++e) { acc0[e] = 0.0f; acc1[e] = 0.0f; }
    acc0 = __builtin_amdgcn_mfma_f32_32x32x16_bf16(w1f[0][0], bfr0, acc0, 0, 0, 0);
    acc0 = __builtin_amdgcn_mfma_f32_32x32x16_bf16(w1f[0][1], bfr1, acc0, 0, 0, 0);
    acc1 = __builtin_amdgcn_mfma_f32_32x32x16_bf16(w1f[1][0], bfr0, acc1, 0, 0, 0);
    acc1 = __builtin_amdgcn_mfma_f32_32x32x16_bf16(w1f[1][1], bfr1, acc1, 0, 0, 0);

    // ---- lrelu + decompose h into packed bf16 pair-dwords ----
    unsigned pkh_[16], pkl_[16];
    #pragma unroll
    for (int m = 0; m < 8; ++m) {
      const float x0 = lrelu(acc0[2 * m]), x1 = lrelu(acc0[2 * m + 1]);
      unsigned h0, h1;
      const float hf0 = truncbf(x0, h0), hf1 = truncbf(x1, h1);
      const unsigned l0 = __float_as_uint(x0 - hf0), l1 = __float_as_uint(x1 - hf1);
      pkh_[m] = (h0 >> 16) | h1;
      pkl_[m] = (l0 >> 16) | (l1 & 0xffff0000u);
    }
    #pragma unroll
    for (int m = 0; m < 8; ++m) {
      const float x0 = lrelu(acc1[2 * m]), x1 = lrelu(acc1[2 * m + 1]);
      unsigned h0, h1;
      const float hf0 = truncbf(x0, h0), hf1 = truncbf(x1, h1);
      const unsigned l0 = __float_as_uint(x0 - hf0), l1 = __float_as_uint(x1 - hf1);
      pkh_[8 + m] = (h0 >> 16) | h1;
      pkl_[8 + m] = (l0 >> 16) | (l1 & 0xffff0000u);
    }

    // ---- layer2: A-frags assembled in-register via half-wave exchange ----
    f32x16 acc2[4];
    #pragma unroll
    for (int jt = 0; jt < 4; ++jt)
      #pragma unroll
      for (int e = 0; e < 16; ++e) acc2[jt][e] = 0.0f;

    #pragma unroll
    for (int ks = 0; ks < 4; ++ks) {
      const int base = (ks >> 1) * 8;
      const int c0 = (ks & 1) * 4;
      unsigned dh[4], dl[4];
      #pragma unroll
      for (int cc = 0; cc < 2; ++cc) {
        {
          const unsigned plo = pkh_[base + c0 + cc];
          const unsigned phi = pkh_[base + c0 + cc + 2];
          const unsigned x = kh2 ? plo : phi;
          const unsigned y = (unsigned)__shfl_xor((int)x, 32);
          dh[cc] = kh2 ? y : plo;
          dh[2 + cc] = kh2 ? phi : y;
        }
        {
          const unsigned plo = pkl_[base + c0 + cc];
          const unsigned phi = pkl_[base + c0 + cc + 2];
          const unsigned x = kh2 ? plo : phi;
          const unsigned y = (unsigned)__shfl_xor((int)x, 32);
          dl[cc] = kh2 ? y : plo;
          dl[2 + cc] = kh2 ? phi : y;
        }
      }
      const bf16x8 Ah = asbf8((u32x4){dh[0], dh[1], dh[2], dh[3]});
      const bf16x8 Al = asbf8((u32x4){dl[0], dl[1], dl[2], dl[3]});
      const int kcb = (ks * 2 + kh2) * 128;
      #pragma unroll
      for (int jt = 0; jt < 4; ++jt) {
        const bf16x8 Bh = *(const bf16x8*)&w2h[(kcb + jt * 32 + col) * 8];
        const bf16x8 Bl = *(const bf16x8*)&w2l[(kcb + jt * 32 + col) * 8];
        acc2[jt] = __builtin_amdgcn_mfma_f32_32x32x16_bf16(Ah, Bh, acc2[jt], 0, 0, 0);
        acc2[jt] = __builtin_amdgcn_mfma_f32_32x32x16_bf16(Ah, Bl, acc2[jt], 0, 0, 0);
        acc2[jt] = __builtin_amdgcn_mfma_f32_32x32x16_bf16(Al, Bh, acc2[jt], 0, 0, 0);
      }
    }

    // ---- segmented max (bias+lrelu applied AFTER max: both monotone/uniform in-batch) ----
    const int bA = __shfl(bi, 0);
    const int bB = __shfl(bi, 31);
    if (bA == bB && (pbase + 32) <= N) {
      // fast path: whole tile in one batch, all rows valid
      #pragma unroll
      for (int jt = 0; jt < 4; ++jt) {
        float m = acc2[jt][0];
        #pragma unroll
        for (int r = 1; r < 16; ++r) m = fmaxf(m, acc2[jt][r]);
        m = fmaxf(m, __shfl_xor(m, 32));
        if (lane < 32) {
          const float s = lrelu(m + b2v[jt]);
          atomicMax(&gf[bA * 128 + jt * 32 + col], f2mono(s));
        }
      }
    } else {
      int pbi[16];
      bool pv[16];
      #pragma unroll
      for (int r = 0; r < 16; ++r) {
        const int rr = (r & 3) + ((r >> 2) << 3) + (kh2 << 2);
        pbi[r] = __shfl(bi, rr);
        pv[r] = (pbase + rr) < N;
      }
      for (int b = bA; b <= bB; ++b) {
        #pragma unroll
        for (int jt = 0; jt < 4; ++jt) {
          float m = -3.0e38f;
          #pragma unroll
          for (int r = 0; r < 16; ++r)
            if (pv[r] && pbi[r] == b) m = fmaxf(m, acc2[jt][r]);
          m = fmaxf(m, __shfl_xor(m, 32));
          if (lane < 32 && m > -2.9e38f) {
            const float s = lrelu(m + b2v[jt]);
            atomicMax(&gf[b * 128 + jt * 32 + col], f2mono(s));
          }
        }
      }
    }
  }
}

// ---------------- decision MLP: [B,132] @ W3 -> lrelu -> @ W4 + b4 ----------------
__global__ __launch_bounds__(128) void sc_final(
    const unsigned* __restrict__ gf, const float* __restrict__ cond,
    const float* __restrict__ W3, const float* __restrict__ b3,
    const float* __restrict__ W4, const float* __restrict__ b4,
    float* __restrict__ out, int B) {
  __shared__ __align__(16) float w3t[128 * 132];  // [j][k]
  __shared__ float b3s[128], w4s[128];
  __shared__ __align__(16) float din[8 * 132];
  __shared__ float wred[16];
  const int t = threadIdx.x;
  for (int k = 0; k < 132; ++k) w3t[t * 132 + k] = W3[k * 128 + t];
  b3s[t] = b3[t];
  w4s[t] = W4[t];
  __syncthreads();

  const int nocts = (B + 7) >> 3;
  for (int oc = blockIdx.x; oc < nocts; oc += gridDim.x) {
    const int rbase = oc << 3;
    #pragma unroll
    for (int r = 0; r < 8; ++r) {
      const int row = rbase + r;
      if (row < B) {
        din[r * 132 + t] = mono2f(gf[row * 128 + t]);
        if (t < 4) din[r * 132 + 128 + t] = cond[row * 4 + t];
      }
    }
    __syncthreads();
    float a8[8];
    #pragma unroll
    for (int r = 0; r < 8; ++r) a8[r] = b3s[t];
    for (int kg = 0; kg < 33; ++kg) {
      const f32x4 wv = *(const f32x4*)&w3t[t * 132 + kg * 4];
      #pragma unroll
      for (int r = 0; r < 8; ++r) {
        const f32x4 dv = *(const f32x4*)&din[r * 132 + kg * 4];
        a8[r] += wv[0] * dv[0] + wv[1] * dv[1] + wv[2] * dv[2] + wv[3] * dv[3];
      }
    }
    const float w4v = w4s[t];
    #pragma unroll
    for (int r = 0; r < 8; ++r) a8[r] = lrelu(a8[r]) * w4v;
    const int lane = t & 63;
    const int wv_ = t >> 6;
    #pragma unroll
    for (int r = 0; r < 8; ++r) {
      float s = a8[r];
      s += __shfl_xor(s, 1);  s += __shfl_xor(s, 2);
      s += __shfl_xor(s, 4);  s += __shfl_xor(s, 8);
      s += __shfl_xor(s, 16); s += __shfl_xor(s, 32);
      if (lane == 0) wred[wv_ * 8 + r] = s;
    }
    __syncthreads();
    if (t < 8) {
      const int row = rbase + t;
      if (row < B) out[row] = wred[t] + wred[8 + t] + b4[0];
    }
    __syncthreads();
  }
}

extern "C" void kernel_launch(void* const* d_in, const int* in_sizes, int n_in,
                              void* d_out, int out_size, void* d_ws, size_t ws_size,
                              hipStream_t stream) {
  const float* muons = (const float*)d_in[0];
  const int* bidx = (const int*)d_in[1];
  const float* cond = (const float*)d_in[2];
  const float* W1 = (const float*)d_in[4];
  const float* b1 = (const float*)d_in[5];
  const float* W2 = (const float*)d_in[6];
  const float* b2 = (const float*)d_in[7];
  const float* W3 = (const float*)d_in[8];
  const float* b3 = (const float*)d_in[9];
  const float* W4 = (const float*)d_in[10];
  const float* b4 = (const float*)d_in[11];
  float* out = (float*)d_out;
  const int N = in_sizes[1];
  const int B = out_size;
  unsigned* gf = (unsigned*)d_ws;  // B*128 mono-encoded uints (8 MB)

  const int total4 = (B * 128) / 4;
  sc_init<<<(total4 + 255) / 256, 256, 0, stream>>>(gf, total4);
  sc_main<<<768, 256, 0, stream>>>(muons, bidx, cond, W1, b1, W2, b2, gf, N);
  sc_final<<<1024, 128, 0, stream>>>(gf, cond, W3, b3, W4, b4, out, B);
  (void)n_in; (void)ws_size;
}